// Round 8
// baseline (116.830 us; speedup 1.0000x reference)
//
#include <hip/hip_runtime.h>
#include <stdint.h>

#define N_ROWS   16384
#define IN_DIM   512
#define CB_DIM   16
#define CB_VOCAB 8192

// ---- k_front geometry: proj blocks 0..511, prep blocks 512..639
#define PROJ_ROWS 128
#define PROJ_GROUPS (N_ROWS / PROJ_ROWS)         // 128
#define KSPLIT 4
#define PROJ_BLOCKS (PROJ_GROUPS * KSPLIT)       // 512
#define PREP_BLOCKS 128

// ---- scan geometry
#define N_RT   (N_ROWS / 16)                     // 1024 row-tiles
#define N_CT   (CB_VOCAB / 16)                   // 512 code-tiles
#define CODEPARTS 16
#define CT_PER_PART (N_CT / CODEPARTS)           // 32
#define N_ROWGRP 64                              // 256 rows per rowgrp

// ---- workspace layout (bytes), ~7.2 MB
#define WS_OFF_XPP  0                            // xp_part: 4 x 1 MB
#define WS_OFF_AFA  (4u << 20)                   // A-frag [A1|A2]: 1 MB
#define WS_OFF_AFB  (5u << 20)                   // A-frag [A1|A3]: 1 MB
#define WS_OFF_BHH  (6u << 20)                   // B-frag [B1;B2]: 512 KB
#define WS_OFF_B31  ((6u << 20) + (512u << 10))  // B-frag [B3;B1]: 512 KB
#define WS_OFF_PART (7u << 20)                   // u64[16384]: 128 KB
#define WS_OFF_CNT  ((7u << 20) + (128u << 10))  // u32[64]

typedef __attribute__((ext_vector_type(8))) short bf16x8;
typedef __attribute__((ext_vector_type(4))) float f32x4;

// monotone float -> uint32 key (order-preserving)
__device__ __forceinline__ unsigned fkey(float f) {
    unsigned u = __float_as_uint(f);
    return (u & 0x80000000u) ? ~u : (u | 0x80000000u);
}

// fp32 -> bf16 bits, round-to-nearest-even
__device__ __forceinline__ unsigned short f2bf(float f) {
    unsigned u = __float_as_uint(f);
    return (unsigned short)((u + 0x7FFFu + ((u >> 16) & 1u)) >> 16);
}
__device__ __forceinline__ float bf2f(unsigned short h) {
    return __uint_as_float(((unsigned)h) << 16);
}

// ---------------- K1: proj (R6-proven 2-row/lane) + CB prep + init ----------
// proj: block b -> row-group g=b>>2 (128 rows), k-part p=b&3 (128 k's);
// wave w covers k-sub [128p+32w,+32); lane owns 2 rows. VALU-bound shape:
// 4 ds_read_b128 feed 32 FMAs. Writes xp_part[p].
// prep: CB -> B-frags; zero part/cnt.
__global__ __launch_bounds__(256, 4)
void k_front(const float* __restrict__ x, const float* __restrict__ P,
             const float* __restrict__ CB, float* __restrict__ xp_part,
             bf16x8* __restrict__ Bhh, bf16x8* __restrict__ B31,
             unsigned long long* __restrict__ part, unsigned* __restrict__ cnt) {
    __shared__ float4 Ps[128 * 4];
    __shared__ float  accs[4][128][17];

    const int wave = threadIdx.x >> 6;
    const int lane = threadIdx.x & 63;

    if (blockIdx.x >= PROJ_BLOCKS) {
        // ---- prep path: zero part/cnt, build CB B-frags ----
        const int pb = blockIdx.x - PROJ_BLOCKS;
        if (threadIdx.x < 128) part[pb * 128 + threadIdx.x] = 0ull;
        if (pb == 0 && threadIdx.x < 64) cnt[threadIdx.x] = 0u;

        const int ct   = pb * 4 + wave;
        const int n    = lane & 15;
        const int quad = lane >> 4;
        const int kh   = (quad & 1) * 8;
        const int lvl  = quad >> 1;
        const int code = ct * 16 + n;

        const float4* b4 = (const float4*)(CB + (size_t)code * CB_DIM + kh);
        float4 a = b4[0], b = b4[1];
        float v[8] = {a.x, a.y, a.z, a.w, b.x, b.y, b.z, b.w};

        bf16x8 shh, s31;
#pragma unroll
        for (int j = 0; j < 8; ++j) {
            float f = v[j];
            unsigned short b1 = f2bf(f);  float r1 = f - bf2f(b1);
            unsigned short b2 = f2bf(r1); float r2 = r1 - bf2f(b2);
            unsigned short b3 = f2bf(r2);
            shh[j] = (short)(lvl ? b2 : b1);
            s31[j] = (short)(lvl ? b1 : b3);
        }
        Bhh[(size_t)ct * 64 + lane] = shh;
        B31[(size_t)ct * 64 + lane] = s31;
        return;
    }

    // ---- proj path (R6/R4 body) ----
    const int g = blockIdx.x >> 2;
    const int p = blockIdx.x & 3;

    for (int i = threadIdx.x; i < 512; i += 256)
        Ps[i] = ((const float4*)P)[p * 512 + i];
    __syncthreads();

    const int row0 = PROJ_ROWS * g + 2 * lane;
    const int kabs = 128 * p + 32 * wave;

    float acc0[16], acc1[16];
#pragma unroll
    for (int c = 0; c < 16; ++c) { acc0[c] = 0.f; acc1[c] = 0.f; }

    const float4* xr0 = (const float4*)(x + (size_t)row0 * IN_DIM + kabs);
    const float4* xr1 = (const float4*)(x + (size_t)(row0 + 1) * IN_DIM + kabs);

#pragma unroll
    for (int i = 0; i < 8; ++i) {
        float4 xa = xr0[i];
        float4 xb = xr1[i];
        float xas[4] = {xa.x, xa.y, xa.z, xa.w};
        float xbs[4] = {xb.x, xb.y, xb.z, xb.w};
#pragma unroll
        for (int kk = 0; kk < 4; ++kk) {
#pragma unroll
            for (int q = 0; q < 4; ++q) {
                float4 pv = Ps[(32 * wave + 4 * i + kk) * 4 + q];
                acc0[4 * q + 0] += xas[kk] * pv.x;
                acc0[4 * q + 1] += xas[kk] * pv.y;
                acc0[4 * q + 2] += xas[kk] * pv.z;
                acc0[4 * q + 3] += xas[kk] * pv.w;
                acc1[4 * q + 0] += xbs[kk] * pv.x;
                acc1[4 * q + 1] += xbs[kk] * pv.y;
                acc1[4 * q + 2] += xbs[kk] * pv.z;
                acc1[4 * q + 3] += xbs[kk] * pv.w;
            }
        }
    }

#pragma unroll
    for (int c = 0; c < 16; ++c) {
        accs[wave][2 * lane][c]     = acc0[c];
        accs[wave][2 * lane + 1][c] = acc1[c];
    }
    __syncthreads();

    float4* xpp = (float4*)xp_part;
#pragma unroll
    for (int it = 0; it < 2; ++it) {
        int idx = threadIdx.x + 256 * it;
        int r = idx >> 2, q = idx & 3;
        float4 s = {0.f, 0.f, 0.f, 0.f};
#pragma unroll
        for (int w = 0; w < 4; ++w) {
            s.x += accs[w][r][4 * q + 0];
            s.y += accs[w][r][4 * q + 1];
            s.z += accs[w][r][4 * q + 2];
            s.w += accs[w][r][4 * q + 3];
        }
        xpp[(size_t)p * (N_ROWS * 4) + (size_t)(PROJ_ROWS * g + r) * 4 + q] = s;
    }
}

// ---------------- K1b: fold partials + 3-way bf16 split -> A-frags ----------
__global__ __launch_bounds__(256, 4)
void k_fold_frag(const float* __restrict__ xp_part,
                 bf16x8* __restrict__ AfragA, bf16x8* __restrict__ AfragB) {
    const int wave = threadIdx.x >> 6;
    const int lane = threadIdx.x & 63;
    const int rt   = blockIdx.x * 4 + wave;
    const int m    = lane & 15;
    const int quad = lane >> 4;
    const int kh   = (quad & 1) * 8;
    const int lvl  = quad >> 1;
    const int row  = rt * 16 + m;

    const float* base = xp_part + (size_t)row * 16 + kh;
    float4 u0 = {0.f,0.f,0.f,0.f}, u1 = {0.f,0.f,0.f,0.f};
#pragma unroll
    for (int p = 0; p < 4; ++p) {
        const float4* b4 = (const float4*)(base + (size_t)p * (N_ROWS * 16));
        float4 a = b4[0], b = b4[1];
        u0.x += a.x; u0.y += a.y; u0.z += a.z; u0.w += a.w;
        u1.x += b.x; u1.y += b.y; u1.z += b.z; u1.w += b.w;
    }
    float v[8] = {u0.x, u0.y, u0.z, u0.w, u1.x, u1.y, u1.z, u1.w};

    bf16x8 sa, sb;
#pragma unroll
    for (int j = 0; j < 8; ++j) {
        float f = v[j];
        unsigned short b1 = f2bf(f);  float r1 = f - bf2f(b1);
        unsigned short b2 = f2bf(r1); float r2 = r1 - bf2f(b2);
        unsigned short b3 = f2bf(r2);
        sa[j] = (short)(lvl ? b2 : b1);
        sb[j] = (short)(lvl ? b3 : b1);
    }
    AfragA[(size_t)rt * 64 + lane] = sa;
    AfragB[(size_t)rt * 64 + lane] = sb;
}

// ---------------- K2: MFMA sim + argmax + last-block finalize ---------------
__global__ __launch_bounds__(256, 4)
void k_scan(const bf16x8* __restrict__ AfragA, const bf16x8* __restrict__ AfragB,
            const bf16x8* __restrict__ Bhh, const bf16x8* __restrict__ B31,
            unsigned long long* __restrict__ part, unsigned* __restrict__ cnt,
            int* __restrict__ out) {
    __shared__ int s_done;
    const int codepart = blockIdx.x & (CODEPARTS - 1);
    const int rowgrp   = blockIdx.x >> 4;
    const int wave     = threadIdx.x >> 6;
    const int lane     = threadIdx.x & 63;
    const int n        = lane & 15;
    const int quad     = lane >> 4;
    const int rt_base  = rowgrp * 16 + wave * 4;

    bf16x8 Aa[4], Ab[4];
#pragma unroll
    for (int t = 0; t < 4; ++t) {
        Aa[t] = AfragA[(size_t)(rt_base + t) * 64 + lane];
        Ab[t] = AfragB[(size_t)(rt_base + t) * 64 + lane];
    }

    float bestv[4][4];
    int   bestc[4][4];
#pragma unroll
    for (int t = 0; t < 4; ++t)
#pragma unroll
        for (int r = 0; r < 4; ++r) { bestv[t][r] = -INFINITY; bestc[t][r] = 0; }

    const int ct0 = codepart * CT_PER_PART;
    size_t ib = (size_t)ct0 * 64;
    bf16x8 nb1  = Bhh[ib + lane];
    bf16x8 nb1s = Bhh[ib + (lane ^ 32)];
    bf16x8 nb3  = B31[ib + lane];

    for (int c = 0; c < CT_PER_PART; ++c) {
        bf16x8 b1 = nb1, b1s = nb1s, b3 = nb3;
        if (c + 1 < CT_PER_PART) {
            size_t ibn = (size_t)(ct0 + c + 1) * 64;
            nb1  = Bhh[ibn + lane];
            nb1s = Bhh[ibn + (lane ^ 32)];
            nb3  = B31[ibn + lane];
        }
#pragma unroll
        for (int t = 0; t < 4; ++t) {
            f32x4 s = __builtin_amdgcn_mfma_f32_16x16x32_bf16(
                          Aa[t], b1, (f32x4){0.f, 0.f, 0.f, 0.f}, 0, 0, 0);
            s = __builtin_amdgcn_mfma_f32_16x16x32_bf16(Aa[t], b1s, s, 0, 0, 0);
            s = __builtin_amdgcn_mfma_f32_16x16x32_bf16(Ab[t], b3,  s, 0, 0, 0);
#pragma unroll
            for (int r = 0; r < 4; ++r) {
                if (s[r] > bestv[t][r]) { bestv[t][r] = s[r]; bestc[t][r] = c; }
            }
        }
    }

    // reduce over the 16 code-class lanes, then device-scope max per row
#pragma unroll
    for (int t = 0; t < 4; ++t) {
#pragma unroll
        for (int r = 0; r < 4; ++r) {
            unsigned code = (unsigned)(codepart * 512 + bestc[t][r] * 16 + n);
            unsigned long long packed =
                ((unsigned long long)fkey(bestv[t][r]) << 32) |
                (unsigned long long)(0xFFFFFFFFu - code);
#pragma unroll
            for (int mk = 1; mk <= 8; mk <<= 1) {
                unsigned long long o = __shfl_xor(packed, mk, 64);
                packed = (o > packed) ? o : packed;
            }
            if (n == 0) {
                int row = (rt_base + t) * 16 + quad * 4 + r;
                atomicMax(&part[row], packed);
            }
        }
    }

    // __syncthreads drains vmcnt -> all this block's atomics are complete
    __syncthreads();
    if (threadIdx.x == 0)
        s_done = (atomicAdd(&cnt[rowgrp], 1u) == (unsigned)(CODEPARTS - 1));
    __syncthreads();

    if (s_done) {
        int row = rowgrp * 256 + threadIdx.x;
        unsigned long long v = atomicAdd(&part[row], 0ull);   // coherent read
        out[row] = (int)(0xFFFFFFFFu - (unsigned)(v & 0xFFFFFFFFull));
    }
}

extern "C" void kernel_launch(void* const* d_in, const int* in_sizes, int n_in,
                              void* d_out, int out_size, void* d_ws, size_t ws_size,
                              hipStream_t stream) {
    const float* x  = (const float*)d_in[0];   // [16384, 512]
    const float* P  = (const float*)d_in[1];   // [512, 16]
    const float* CB = (const float*)d_in[2];   // [8192, 16]
    int* out = (int*)d_out;                    // [16384] int32

    char* ws = (char*)d_ws;
    float*  xp_part = (float*)(ws + WS_OFF_XPP);
    bf16x8* AfragA  = (bf16x8*)(ws + WS_OFF_AFA);
    bf16x8* AfragB  = (bf16x8*)(ws + WS_OFF_AFB);
    bf16x8* Bhh     = (bf16x8*)(ws + WS_OFF_BHH);
    bf16x8* B31     = (bf16x8*)(ws + WS_OFF_B31);
    unsigned long long* part = (unsigned long long*)(ws + WS_OFF_PART);
    unsigned* cnt   = (unsigned*)(ws + WS_OFF_CNT);

    k_front<<<PROJ_BLOCKS + PREP_BLOCKS, 256, 0, stream>>>(
        x, P, CB, xp_part, Bhh, B31, part, cnt);                   // 640 blocks
    k_fold_frag<<<N_RT / 4, 256, 0, stream>>>(xp_part, AfragA, AfragB); // 256 blocks
    k_scan<<<N_ROWGRP * CODEPARTS, 256, 0, stream>>>(
        AfragA, AfragB, Bhh, B31, part, cnt, out);                 // 1024 blocks
}

// Round 9
// 113.550 us; speedup vs baseline: 1.0289x; 1.0289x over previous
//
#include <hip/hip_runtime.h>
#include <stdint.h>

#define N_ROWS   16384
#define IN_DIM   512
#define CB_DIM   16
#define CB_VOCAB 8192

// ---- K1 geometry
#define PROJ_BLOCKS 512                          // 32 rows each, full K
#define PREP_BLOCKS 128                          // 4 code-tiles each

// ---- scan geometry
#define N_RT   (N_ROWS / 16)                     // 1024 row-tiles
#define N_CT   (CB_VOCAB / 16)                   // 512 code-tiles
#define CODEPARTS 16
#define CT_PER_PART (N_CT / CODEPARTS)           // 32
#define N_ROWGRP 64                              // 256 rows per rowgrp

// ---- workspace layout (bytes), ~3.2 MB
#define WS_OFF_AFA  0                            // A-frag [A1|A2]: 1 MB
#define WS_OFF_AFB  (1u << 20)                   // A-frag [A1|A3]: 1 MB
#define WS_OFF_BHH  (2u << 20)                   // B-frag [B1;B2]: 512 KB
#define WS_OFF_B31  ((2u << 20) + (512u << 10))  // B-frag [B3;B1]: 512 KB
#define WS_OFF_PART (3u << 20)                   // u64[16384]: 128 KB
#define WS_OFF_CNT  ((3u << 20) + (128u << 10))  // u32[64]

typedef __attribute__((ext_vector_type(8))) short bf16x8;
typedef __attribute__((ext_vector_type(4))) float f32x4;

// monotone float -> uint32 key (order-preserving)
__device__ __forceinline__ unsigned fkey(float f) {
    unsigned u = __float_as_uint(f);
    return (u & 0x80000000u) ? ~u : (u | 0x80000000u);
}

// fp32 -> bf16 bits, round-to-nearest-even
__device__ __forceinline__ unsigned short f2bf(float f) {
    unsigned u = __float_as_uint(f);
    return (unsigned short)((u + 0x7FFFu + ((u >> 16) & 1u)) >> 16);
}
__device__ __forceinline__ float bf2f(unsigned short h) {
    return __uint_as_float(((unsigned)h) << 16);
}

// ---------------- K1: proj + fold + A-frag (blocks 0..511); CB prep + init
// (blocks 512..639).
// proj: block = 32 rows x full K=512. Wave w, lane-half h cover k in
// [128w+64h, +64); lane owns 1 row. 8 k-partials in LDS, folded in-block,
// 3-way bf16 split, A-frags written directly (no xp roundtrip).
__global__ __launch_bounds__(256, 2)
void k_front(const float* __restrict__ x, const float* __restrict__ P,
             const float* __restrict__ CB,
             bf16x8* __restrict__ AfragA, bf16x8* __restrict__ AfragB,
             bf16x8* __restrict__ Bhh, bf16x8* __restrict__ B31,
             unsigned long long* __restrict__ part, unsigned* __restrict__ cnt) {
    __shared__ float4 Ps[IN_DIM * 4];            // P [512][16]: 32 KB
    __shared__ float  accs[8][32][20];           // 8 k-partials x 32 rows: 20 KB

    const int wave = threadIdx.x >> 6;
    const int lane = threadIdx.x & 63;

    if (blockIdx.x >= PROJ_BLOCKS) {
        // ---- prep path: zero part/cnt, build CB B-frags ----
        const int pb = blockIdx.x - PROJ_BLOCKS;
        if (threadIdx.x < 128) part[pb * 128 + threadIdx.x] = 0ull;
        if (pb == 0 && threadIdx.x < 64) cnt[threadIdx.x] = 0u;

        const int ct   = pb * 4 + wave;
        const int n    = lane & 15;
        const int quad = lane >> 4;
        const int kh   = (quad & 1) * 8;
        const int lvl  = quad >> 1;
        const int code = ct * 16 + n;

        const float4* b4 = (const float4*)(CB + (size_t)code * CB_DIM + kh);
        float4 a = b4[0], b = b4[1];
        float v[8] = {a.x, a.y, a.z, a.w, b.x, b.y, b.z, b.w};

        bf16x8 shh, s31;
#pragma unroll
        for (int j = 0; j < 8; ++j) {
            float f = v[j];
            unsigned short b1 = f2bf(f);  float r1 = f - bf2f(b1);
            unsigned short b2 = f2bf(r1); float r2 = r1 - bf2f(b2);
            unsigned short b3 = f2bf(r2);
            shh[j] = (short)(lvl ? b2 : b1);
            s31[j] = (short)(lvl ? b1 : b3);
        }
        Bhh[(size_t)ct * 64 + lane] = shh;
        B31[(size_t)ct * 64 + lane] = s31;
        return;
    }

    // ---- proj path ----
    const int b = blockIdx.x;
    for (int i = threadIdx.x; i < IN_DIM * 4; i += 256)
        Ps[i] = ((const float4*)P)[i];
    __syncthreads();

    const int r32   = lane & 31;
    const int khalf = lane >> 5;
    const int row   = b * 32 + r32;
    const int kb    = 128 * wave + 64 * khalf;   // this lane's absolute k base

    float acc[16];
#pragma unroll
    for (int c = 0; c < 16; ++c) acc[c] = 0.0f;

    const float4* xr = (const float4*)(x + (size_t)row * IN_DIM + kb);

#pragma unroll 4
    for (int i = 0; i < 16; ++i) {               // 16 float4s = 64 k's
        float4 xv = xr[i];
        float xs[4] = {xv.x, xv.y, xv.z, xv.w};
#pragma unroll
        for (int kk = 0; kk < 4; ++kk) {
#pragma unroll
            for (int q = 0; q < 4; ++q) {
                float4 pv = Ps[(kb + 4 * i + kk) * 4 + q];
                acc[4 * q + 0] += xs[kk] * pv.x;
                acc[4 * q + 1] += xs[kk] * pv.y;
                acc[4 * q + 2] += xs[kk] * pv.z;
                acc[4 * q + 3] += xs[kk] * pv.w;
            }
        }
    }

    const int pslot = wave * 2 + khalf;
#pragma unroll
    for (int c = 0; c < 16; ++c) accs[pslot][r32][c] = acc[c];
    __syncthreads();

    // fold 8 partials + 3-way split + emit A-frags (2 row-tiles per block)
    if (threadIdx.x < 128) {
        const int rtl  = threadIdx.x >> 6;       // 0/1
        const int l2   = threadIdx.x & 63;
        const int m    = l2 & 15;
        const int quad = l2 >> 4;
        const int kh   = (quad & 1) * 8;
        const int lvl  = quad >> 1;
        const int rloc = rtl * 16 + m;

        float v[8];
#pragma unroll
        for (int j = 0; j < 8; ++j) v[j] = 0.0f;
#pragma unroll
        for (int p = 0; p < 8; ++p) {
#pragma unroll
            for (int j = 0; j < 8; ++j) v[j] += accs[p][rloc][kh + j];
        }

        bf16x8 sa, sb;
#pragma unroll
        for (int j = 0; j < 8; ++j) {
            float f = v[j];
            unsigned short b1 = f2bf(f);  float r1 = f - bf2f(b1);
            unsigned short b2 = f2bf(r1); float r2 = r1 - bf2f(b2);
            unsigned short b3 = f2bf(r2);
            sa[j] = (short)(lvl ? b2 : b1);
            sb[j] = (short)(lvl ? b3 : b1);
        }
        AfragA[(size_t)(2 * b + rtl) * 64 + l2] = sa;
        AfragB[(size_t)(2 * b + rtl) * 64 + l2] = sb;
    }
}

// ---------------- K2: MFMA sim + argmax + last-block finalize ---------------
// grid 1024 = 64 rowgrps x 16 codeparts; wave = 4 row-tiles x 32 code-tiles.
// 3 chained bf16 MFMAs per tile (fp32-accurate 3-way split), SW-pipelined
// B-frag loads. Cross-block argmax via device-scope atomicMax(u64); the 16th
// block to finish a rowgrp decodes part[] -> out[] (no extra dispatch).
__global__ __launch_bounds__(256, 4)
void k_scan(const bf16x8* __restrict__ AfragA, const bf16x8* __restrict__ AfragB,
            const bf16x8* __restrict__ Bhh, const bf16x8* __restrict__ B31,
            unsigned long long* __restrict__ part, unsigned* __restrict__ cnt,
            int* __restrict__ out) {
    __shared__ int s_done;
    const int codepart = blockIdx.x & (CODEPARTS - 1);
    const int rowgrp   = blockIdx.x >> 4;
    const int wave     = threadIdx.x >> 6;
    const int lane     = threadIdx.x & 63;
    const int n        = lane & 15;
    const int quad     = lane >> 4;
    const int rt_base  = rowgrp * 16 + wave * 4;

    bf16x8 Aa[4], Ab[4];
#pragma unroll
    for (int t = 0; t < 4; ++t) {
        Aa[t] = AfragA[(size_t)(rt_base + t) * 64 + lane];
        Ab[t] = AfragB[(size_t)(rt_base + t) * 64 + lane];
    }

    float bestv[4][4];
    int   bestc[4][4];
#pragma unroll
    for (int t = 0; t < 4; ++t)
#pragma unroll
        for (int r = 0; r < 4; ++r) { bestv[t][r] = -INFINITY; bestc[t][r] = 0; }

    const int ct0 = codepart * CT_PER_PART;
    size_t ib = (size_t)ct0 * 64;
    bf16x8 nb1  = Bhh[ib + lane];
    bf16x8 nb1s = Bhh[ib + (lane ^ 32)];
    bf16x8 nb3  = B31[ib + lane];

    for (int c = 0; c < CT_PER_PART; ++c) {
        bf16x8 b1 = nb1, b1s = nb1s, b3 = nb3;
        if (c + 1 < CT_PER_PART) {
            size_t ibn = (size_t)(ct0 + c + 1) * 64;
            nb1  = Bhh[ibn + lane];
            nb1s = Bhh[ibn + (lane ^ 32)];
            nb3  = B31[ibn + lane];
        }
#pragma unroll
        for (int t = 0; t < 4; ++t) {
            f32x4 s = __builtin_amdgcn_mfma_f32_16x16x32_bf16(
                          Aa[t], b1, (f32x4){0.f, 0.f, 0.f, 0.f}, 0, 0, 0);
            s = __builtin_amdgcn_mfma_f32_16x16x32_bf16(Aa[t], b1s, s, 0, 0, 0);
            s = __builtin_amdgcn_mfma_f32_16x16x32_bf16(Ab[t], b3,  s, 0, 0, 0);
#pragma unroll
            for (int r = 0; r < 4; ++r) {
                if (s[r] > bestv[t][r]) { bestv[t][r] = s[r]; bestc[t][r] = c; }
            }
        }
    }

    // reduce over the 16 code-class lanes, then device-scope max per row
#pragma unroll
    for (int t = 0; t < 4; ++t) {
#pragma unroll
        for (int r = 0; r < 4; ++r) {
            unsigned code = (unsigned)(codepart * 512 + bestc[t][r] * 16 + n);
            unsigned long long packed =
                ((unsigned long long)fkey(bestv[t][r]) << 32) |
                (unsigned long long)(0xFFFFFFFFu - code);
#pragma unroll
            for (int mk = 1; mk <= 8; mk <<= 1) {
                unsigned long long o = __shfl_xor(packed, mk, 64);
                packed = (o > packed) ? o : packed;
            }
            if (n == 0) {
                int row = (rt_base + t) * 16 + quad * 4 + r;
                atomicMax(&part[row], packed);
            }
        }
    }

    // __syncthreads drains vmcnt -> all this block's atomics are complete
    __syncthreads();
    if (threadIdx.x == 0)
        s_done = (atomicAdd(&cnt[rowgrp], 1u) == (unsigned)(CODEPARTS - 1));
    __syncthreads();

    if (s_done) {
        int row = rowgrp * 256 + threadIdx.x;
        unsigned long long v = atomicAdd(&part[row], 0ull);   // coherent read
        out[row] = (int)(0xFFFFFFFFu - (unsigned)(v & 0xFFFFFFFFull));
    }
}

extern "C" void kernel_launch(void* const* d_in, const int* in_sizes, int n_in,
                              void* d_out, int out_size, void* d_ws, size_t ws_size,
                              hipStream_t stream) {
    const float* x  = (const float*)d_in[0];   // [16384, 512]
    const float* P  = (const float*)d_in[1];   // [512, 16]
    const float* CB = (const float*)d_in[2];   // [8192, 16]
    int* out = (int*)d_out;                    // [16384] int32

    char* ws = (char*)d_ws;
    bf16x8* AfragA = (bf16x8*)(ws + WS_OFF_AFA);
    bf16x8* AfragB = (bf16x8*)(ws + WS_OFF_AFB);
    bf16x8* Bhh    = (bf16x8*)(ws + WS_OFF_BHH);
    bf16x8* B31    = (bf16x8*)(ws + WS_OFF_B31);
    unsigned long long* part = (unsigned long long*)(ws + WS_OFF_PART);
    unsigned* cnt  = (unsigned*)(ws + WS_OFF_CNT);

    k_front<<<PROJ_BLOCKS + PREP_BLOCKS, 256, 0, stream>>>(
        x, P, CB, AfragA, AfragB, Bhh, B31, part, cnt);            // 640 blocks
    k_scan<<<N_ROWGRP * CODEPARTS, 256, 0, stream>>>(
        AfragA, AfragB, Bhh, B31, part, cnt, out);                 // 1024 blocks
}